// Round 1
// 1016.192 us; speedup vs baseline: 1.1753x; 1.1753x over previous
//
#include <hip/hip_runtime.h>
#include <cfloat>
#include <cstdint>

#define D_IN  2048
#define D_HID 16384
#define TOPK  16
#define BATCH 4096

#define NBINS    4096      // 12-bit histogram: sign + 8 exp + 3 mantissa bits
#define CBUF     512       // candidate cap per row
#define TARGET   32        // min candidates above threshold (margin over 16)

typedef unsigned short ushort_t;
typedef __attribute__((ext_vector_type(8))) short short8;
typedef __attribute__((ext_vector_type(4))) float floatx4;

// ---------------------------------------------------------------------------
// fp32 -> bf16 (RNE) conversion, 8 elements/thread, 16B stores
// ---------------------------------------------------------------------------
__device__ __forceinline__ ushort_t f2bf(float f) {
    unsigned u = __float_as_uint(f);
    u = (u + 0x7FFFu + ((u >> 16) & 1u)) >> 16;
    return (ushort_t)u;
}

__global__ __launch_bounds__(256) void convert_bf16(
    const float* __restrict__ src, ushort_t* __restrict__ dst, int n8)
{
    const int i = blockIdx.x * 256 + threadIdx.x;
    if (i >= n8) return;
    const float4* s4 = (const float4*)src;
    float4 a = s4[2 * i];
    float4 b = s4[2 * i + 1];
    union { ushort_t u[8]; short8 v; } p;
    p.u[0] = f2bf(a.x); p.u[1] = f2bf(a.y); p.u[2] = f2bf(a.z); p.u[3] = f2bf(a.w);
    p.u[4] = f2bf(b.x); p.u[5] = f2bf(b.y); p.u[6] = f2bf(b.z); p.u[7] = f2bf(b.w);
    *(short8*)(dst + (size_t)i * 8) = p.v;
}

// ---------------------------------------------------------------------------
// Coarse encode GEMM, bf16 MFMA (m97 structure):
// y_bf16[M, D_HID] = x_bf16[M, D_IN] * W_bf16[D_HID, D_IN]^T + bias
// 128x128 tile, 4 waves (2x2 of 64x64), 16x16x32 MFMA, BK=32,
// global_load_lds width-16 staging, 2-barrier K-loop.
// ---------------------------------------------------------------------------
#define BK 32

__global__ __launch_bounds__(256) void encode_mfma(
    const ushort_t* __restrict__ A,    // [M, D_IN] bf16 bits (x)
    const ushort_t* __restrict__ B,    // [D_HID, D_IN] bf16 bits (W)
    const float* __restrict__ bias,    // [D_HID]
    ushort_t* __restrict__ Y)          // [M, D_HID] bf16 bits
{
    __shared__ ushort_t As[128 * BK];  // 8 KB, row-major rows of 32 bf16 (64 B)
    __shared__ ushort_t Bs[128 * BK];  // 8 KB

    const int tid = threadIdx.x;
    const int wv = tid >> 6;           // 0..3
    const int ln = tid & 63;
    const int tileM = blockIdx.y * 128;
    const int tileN = blockIdx.x * 128;
    const int waveM = (wv & 1) * 64;
    const int waveN = (wv >> 1) * 64;

    floatx4 acc[4][4] = {};

    // staging: wave wv covers tile rows [wv*32, wv*32+32), 2 issues of 16 rows.
    // lane ln -> row (ln>>2), 16B chunk (ln&3); LDS dest = base + ln*16 (HW rule)
    const int lrow = ln >> 2;
    const int lkof = (ln & 3) * 8;
    const ushort_t* Ag = A + (size_t)(tileM + wv * 32 + lrow) * D_IN + lkof;
    const ushort_t* Bg = B + (size_t)(tileN + wv * 32 + lrow) * D_IN + lkof;
    ushort_t* AsW = As + (wv * 32) * BK;
    ushort_t* BsW = Bs + (wv * 32) * BK;

    // fragment read mapping (verified layouts)
    const int fcol = ln & 15;          // m (A) / n (B) within 16-tile
    const int fk   = (ln >> 4) * 8;    // k offset

    for (int k0 = 0; k0 < D_IN; k0 += BK) {
        __syncthreads();  // previous tile fully consumed
        __builtin_amdgcn_global_load_lds(
            (const __attribute__((address_space(1))) unsigned*)(Ag + k0),
            (__attribute__((address_space(3))) unsigned*)AsW, 16, 0, 0);
        __builtin_amdgcn_global_load_lds(
            (const __attribute__((address_space(1))) unsigned*)(Ag + k0 + (size_t)16 * D_IN),
            (__attribute__((address_space(3))) unsigned*)(AsW + 16 * BK), 16, 0, 0);
        __builtin_amdgcn_global_load_lds(
            (const __attribute__((address_space(1))) unsigned*)(Bg + k0),
            (__attribute__((address_space(3))) unsigned*)BsW, 16, 0, 0);
        __builtin_amdgcn_global_load_lds(
            (const __attribute__((address_space(1))) unsigned*)(Bg + k0 + (size_t)16 * D_IN),
            (__attribute__((address_space(3))) unsigned*)(BsW + 16 * BK), 16, 0, 0);
        __syncthreads();  // vmcnt drained -> tile resident

        short8 af[4], bfr[4];
#pragma unroll
        for (int i = 0; i < 4; ++i)
            af[i] = *(const short8*)(As + (waveM + i * 16 + fcol) * BK + fk);
#pragma unroll
        for (int j = 0; j < 4; ++j)
            bfr[j] = *(const short8*)(Bs + (waveN + j * 16 + fcol) * BK + fk);
#pragma unroll
        for (int i = 0; i < 4; ++i)
#pragma unroll
            for (int j = 0; j < 4; ++j)
                acc[i][j] = __builtin_amdgcn_mfma_f32_16x16x32_bf16(
                    af[i], bfr[j], acc[i][j], 0, 0, 0);
    }

    // epilogue: C/D layout col=lane&15, row=(lane>>4)*4+reg
    const int orow = (ln >> 4) * 4;
    const int ocol = ln & 15;
#pragma unroll
    for (int j = 0; j < 4; ++j) {
        const int gcol = tileN + waveN + j * 16 + ocol;
        const float bc = bias[gcol];
#pragma unroll
        for (int i = 0; i < 4; ++i) {
            const int grow = tileM + waveM + i * 16 + orow;
#pragma unroll
            for (int r = 0; r < 4; ++r)
                Y[(size_t)(grow + r) * D_HID + gcol] = f2bf(acc[i][j][r] + bc);
        }
    }
}

// ---------------------------------------------------------------------------
// Histogram threshold select on bf16 y: emit UNORDERED superset of the
// top-TARGET coarse elements per row (exact ranking by refine_kernel).
// key16 = monotonic 16-bit transform of bf16 bits.
// ---------------------------------------------------------------------------
__device__ __forceinline__ unsigned bf2key(unsigned u) {
    return (u & 0x8000u) ? (~u & 0xFFFFu) : (u | 0x8000u);
}

__global__ __launch_bounds__(256) void topk_select(
    const ushort_t* __restrict__ y,    // [chunkM, D_HID] bf16
    int* __restrict__ cand,            // [BATCH, CBUF]
    int* __restrict__ ccount,          // [BATCH]
    int rowBase)
{
    __shared__ unsigned hist[NBINS];   // 16 KB
    __shared__ unsigned psuf[257];
    __shared__ int sBstar;
    __shared__ unsigned scnt;

    const int tid = threadIdx.x;
    const int row = rowBase + blockIdx.x;
    const short8* yr8 = (const short8*)(y + (size_t)blockIdx.x * D_HID);

    for (int i = tid; i < NBINS; i += 256) hist[i] = 0;
    if (tid == 0) { sBstar = 0; scnt = 0; }
    __syncthreads();

    // Pass 1: histogram of key16 >> 4
    for (int j = 0; j < 8; ++j) {
        union { short8 v; ushort_t u[8]; } p;
        p.v = yr8[tid + j * 256];
#pragma unroll
        for (int c = 0; c < 8; ++c)
            atomicAdd(&hist[bf2key(p.u[c]) >> 4], 1u);
    }
    __syncthreads();

    {
        unsigned s = 0;
#pragma unroll
        for (int i = 0; i < 16; ++i) s += hist[tid * 16 + i];
        psuf[tid] = s;
    }
    __syncthreads();
    if (tid == 0) {
        unsigned run = 0;
        for (int t = 255; t >= 0; --t) { run += psuf[t]; psuf[t] = run; }
        psuf[256] = 0;
    }
    __syncthreads();
    {
        unsigned run = psuf[tid + 1];
        for (int b = tid * 16 + 15; b >= tid * 16; --b) {
            run += hist[b];
            if (run >= TARGET) { atomicMax(&sBstar, b); break; }
        }
    }
    __syncthreads();
    const unsigned keyT = ((unsigned)sBstar) << 4;

    // Pass 2: compact candidate indices (unordered)
    for (int j = 0; j < 8; ++j) {
        const int i8 = tid + j * 256;
        union { short8 v; ushort_t u[8]; } p;
        p.v = yr8[i8];
#pragma unroll
        for (int c = 0; c < 8; ++c) {
            if (bf2key(p.u[c]) >= keyT) {
                unsigned pos = atomicAdd(&scnt, 1u);
                if (pos < CBUF) cand[(size_t)row * CBUF + pos] = i8 * 8 + c;
            }
        }
    }
    __syncthreads();
    if (tid == 0) ccount[row] = (int)min(scnt, (unsigned)CBUF);
}

// ---------------------------------------------------------------------------
// fp64 refinement on the ORIGINAL fp32 inputs: recompute candidate dot
// products exactly, rank (value desc, idx asc), emit top-16 vals + idxs.
//
// v2 (MLP restructure): the previous version compiled the dot loop rolled
// (VGPR_Count=20) -> one outstanding 4B load + serial fp64 chain, pure
// latency-bound (VALUBusy 18%, HBM 20%).  Now:
//   - each lane's 8 float4 slices of the x row are hoisted into REGISTERS
//     (identical for every candidate) -> no LDS in the inner chain
//   - per candidate: 8 unrolled coalesced float4 loads of the W row
//     (8 KB/wave outstanding) feeding 4 independent fp64 accumulators
//   - top-16 loop: wave-level shfl argmax + 4-entry cross-wave merge
//     (32 barriers instead of 144)
// ---------------------------------------------------------------------------
__global__ __launch_bounds__(256, 4) void refine_kernel(
    const float* __restrict__ x,       // [BATCH, D_IN]
    const float* __restrict__ W,       // [D_HID, D_IN]
    const float* __restrict__ bias,    // [D_HID]
    const int* __restrict__ cand,      // [BATCH, CBUF]
    const int* __restrict__ ccount,    // [BATCH]
    float* __restrict__ vals,          // [BATCH, TOPK]
    int* __restrict__ idxs)            // [BATCH, TOPK]
{
    __shared__ double sdot[CBUF];      // 4 KB
    __shared__ int    sidx[CBUF];      // 2 KB
    __shared__ double rdv[4];
    __shared__ int    rdc[4];

    const int b = blockIdx.x;
    const int tid = threadIdx.x;
    const int C = ccount[b];

    for (int c = tid; c < C; c += 256) sidx[c] = cand[(size_t)b * CBUF + c];
    __syncthreads();

    const int wave = tid >> 6;
    const int lane = tid & 63;

    // x-row slices for this lane: same for every candidate -> registers.
    const float4* xg4 = (const float4*)(x + (size_t)b * D_IN);
    float4 xr[8];
#pragma unroll
    for (int i = 0; i < 8; ++i) xr[i] = xg4[lane + i * 64];

    for (int c = wave; c < C; c += 4) {
        const int h = sidx[c];
        const float4* wr4 = (const float4*)(W + (size_t)h * D_IN);
        const float bh = bias[h];      // issue early, consumed at the end
        double a0 = 0.0, a1 = 0.0, a2 = 0.0, a3 = 0.0;
#pragma unroll
        for (int i = 0; i < 8; ++i) {
            float4 w = wr4[lane + i * 64];
            a0 += (double)xr[i].x * (double)w.x;
            a1 += (double)xr[i].y * (double)w.y;
            a2 += (double)xr[i].z * (double)w.z;
            a3 += (double)xr[i].w * (double)w.w;
        }
        double acc = (a0 + a1) + (a2 + a3);
#pragma unroll
        for (int off = 32; off > 0; off >>= 1)
            acc += __shfl_down(acc, off, 64);
        if (lane == 0) sdot[c] = acc + (double)bh;
    }
    __syncthreads();

    for (int k = 0; k < TOPK; ++k) {
        double bv = -1.0e300; int bc = -1;
        for (int c = tid; c < C; c += 256) {
            double v = sdot[c];
            if (v > bv || (v == bv && bc >= 0 && sidx[c] < sidx[bc])) {
                bv = v; bc = c;
            }
        }
        // wave-level argmax (value desc, idx asc), no barriers
#pragma unroll
        for (int off = 32; off > 0; off >>= 1) {
            double v2 = __shfl_down(bv, off, 64);
            int    c2 = __shfl_down(bc, off, 64);
            bool better = (v2 > bv) ||
                (v2 == bv && c2 >= 0 &&
                 (bc < 0 || sidx[c2] < sidx[bc]));
            if (better) { bv = v2; bc = c2; }
        }
        if (lane == 0) { rdv[wave] = bv; rdc[wave] = bc; }
        __syncthreads();
        if (tid == 0) {
            double fv = rdv[0]; int fc = rdc[0];
#pragma unroll
            for (int w = 1; w < 4; ++w) {
                double v2 = rdv[w]; int c2 = rdc[w];
                bool better = (v2 > fv) ||
                    (v2 == fv && c2 >= 0 &&
                     (fc < 0 || sidx[c2] < sidx[fc]));
                if (better) { fv = v2; fc = c2; }
            }
            vals[(size_t)b * TOPK + k] = (float)fv;
            idxs[(size_t)b * TOPK + k] = sidx[fc];
            sdot[fc] = -1.0e300;
        }
        __syncthreads();
    }
}

// ---------------------------------------------------------------------------
// Decode: out[b, :] = sum_k vals[b,k] * W[idx[b,k], :]  (W = w_enc_w, fp32)
// Also writes idx as float into the second output region.
// ---------------------------------------------------------------------------
__global__ __launch_bounds__(256) void decode_kernel(
    const float* __restrict__ vals,
    const int* __restrict__ idxs,
    const float* __restrict__ W,       // [D_HID, D_IN]
    float* __restrict__ out,           // [BATCH, D_IN]
    float* __restrict__ idxOut)        // [BATCH, TOPK] as float
{
    __shared__ float sv[TOPK];
    __shared__ int   si[TOPK];
    const int b = blockIdx.x;
    const int tid = threadIdx.x;

    if (tid < TOPK) {
        float vv = vals[(size_t)b * TOPK + tid];
        int   ii = idxs[(size_t)b * TOPK + tid];
        sv[tid] = vv; si[tid] = ii;
        idxOut[(size_t)b * TOPK + tid] = (float)ii;
    }
    __syncthreads();

    const float4* W4 = (const float4*)W;
    float4* out4 = (float4*)(out + (size_t)b * D_IN);
    for (int d4 = tid; d4 < D_IN / 4; d4 += 256) {
        float4 acc = {0.f, 0.f, 0.f, 0.f};
#pragma unroll
        for (int k = 0; k < TOPK; ++k) {
            float4 w = W4[(size_t)si[k] * (D_IN / 4) + d4];
            float s = sv[k];
            acc.x += s * w.x; acc.y += s * w.y;
            acc.z += s * w.z; acc.w += s * w.w;
        }
        out4[d4] = acc;
    }
}

// ---------------------------------------------------------------------------
extern "C" void kernel_launch(void* const* d_in, const int* in_sizes, int n_in,
                              void* d_out, int out_size, void* d_ws, size_t ws_size,
                              hipStream_t stream)
{
    const float* x    = (const float*)d_in[0];  // [BATCH, D_IN]
    const float* Wenc = (const float*)d_in[1];  // [D_HID, D_IN]
    const float* bias = (const float*)d_in[2];  // [D_HID]
    // d_in[3] = w_emb_w — mathematically Wenc^T, unused.

    float* out    = (float*)d_out;                   // [BATCH, D_IN] fp32
    float* idxOut = out + (size_t)BATCH * D_IN;      // [BATCH, TOPK] as fp32

    char* ws = (char*)d_ws;
    size_t off = 0;
    int*      cand   = (int*)(ws + off);      off += (size_t)BATCH * CBUF * 4;   // 8 MB
    int*      ccount = (int*)(ws + off);      off += (size_t)BATCH * 4;
    float*    vals   = (float*)(ws + off);    off += (size_t)BATCH * TOPK * 4;
    int*      idxs   = (int*)(ws + off);      off += (size_t)BATCH * TOPK * 4;
    off = (off + 255) & ~(size_t)255;
    ushort_t* xbf    = (ushort_t*)(ws + off); off += (size_t)BATCH * D_IN * 2;   // 16 MB
    ushort_t* wbf    = (ushort_t*)(ws + off); off += (size_t)D_HID * D_IN * 2;   // 64 MB
    const size_t head = (off + 255) & ~(size_t)255;
    ushort_t* ybf = (ushort_t*)(ws + head);

    int chunk = BATCH;
    while (chunk > 128 && head + (size_t)chunk * D_HID * 2 > ws_size) chunk >>= 1;

    const int nx8 = BATCH * D_IN / 8;       // 1,048,576
    const int nw8 = D_HID * D_IN / 8;       // 4,194,304
    convert_bf16<<<(nx8 + 255) / 256, 256, 0, stream>>>(x, xbf, nx8);
    convert_bf16<<<(nw8 + 255) / 256, 256, 0, stream>>>(Wenc, wbf, nw8);

    for (int r0 = 0; r0 < BATCH; r0 += chunk) {
        dim3 g(D_HID / 128, chunk / 128);
        encode_mfma<<<g, 256, 0, stream>>>(xbf + (size_t)r0 * D_IN, wbf, bias, ybf);
        topk_select<<<chunk, 256, 0, stream>>>(ybf, cand, ccount, r0);
    }
    refine_kernel<<<BATCH, 256, 0, stream>>>(x, Wenc, bias, cand, ccount, vals, idxs);
    decode_kernel<<<BATCH, 256, 0, stream>>>(vals, idxs, Wenc, out, idxOut);
}

// Round 2
// 950.141 us; speedup vs baseline: 1.2570x; 1.0695x over previous
//
#include <hip/hip_runtime.h>
#include <cfloat>
#include <cstdint>

#define D_IN  2048
#define D_HID 16384
#define TOPK  16
#define BATCH 4096

#define NBINS    4096      // 12-bit histogram: sign + 8 exp + 3 mantissa bits
#define CBUF     512       // candidate cap per row
#define TARGET   32        // min candidates above threshold (margin over 16)

typedef unsigned short ushort_t;
typedef __attribute__((ext_vector_type(8))) short short8;
typedef __attribute__((ext_vector_type(4))) float floatx4;

// ---------------------------------------------------------------------------
// fp32 -> bf16 (RNE) conversion, 8 elements/thread, 16B stores
// ---------------------------------------------------------------------------
__device__ __forceinline__ ushort_t f2bf(float f) {
    unsigned u = __float_as_uint(f);
    u = (u + 0x7FFFu + ((u >> 16) & 1u)) >> 16;
    return (ushort_t)u;
}

__global__ __launch_bounds__(256) void convert_bf16(
    const float* __restrict__ src, ushort_t* __restrict__ dst, int n8)
{
    const int i = blockIdx.x * 256 + threadIdx.x;
    if (i >= n8) return;
    const float4* s4 = (const float4*)src;
    float4 a = s4[2 * i];
    float4 b = s4[2 * i + 1];
    union { ushort_t u[8]; short8 v; } p;
    p.u[0] = f2bf(a.x); p.u[1] = f2bf(a.y); p.u[2] = f2bf(a.z); p.u[3] = f2bf(a.w);
    p.u[4] = f2bf(b.x); p.u[5] = f2bf(b.y); p.u[6] = f2bf(b.z); p.u[7] = f2bf(b.w);
    *(short8*)(dst + (size_t)i * 8) = p.v;
}

// ---------------------------------------------------------------------------
// Coarse encode GEMM, bf16 MFMA — 256x256 8-phase template (m201 structure):
//   BM=BN=256, BK=64, 8 waves (2M x 4N), per-wave output 128x64,
//   LDS 128 KB = 2 bufs x {A0,A1,B0,B1} regions of 16 KB,
//   region A_mq: i = wm*64+r  -> global row tileM + wm*128 + mq*64 + r
//   region B_nq: i = wn*32+r  -> global row tileN + wn*64  + nq*32 + r
//   XOR bank swizzle (both-sides): phys_k_hw = log_k_hw ^ ((row&7)<<3)
//     (global_load_lds writes linearly -> source is PRE-swizzled; ds_read
//      applies the same involution -> lanes spread over 8 16B slots, 2-way)
//   Phases per iter (2 K-tiles): quadrant order (mq,nq)=00,01,10,11 per tile.
//   Register reuse: A frags live P1->P2 / P3->P4; B0 frags live P1->P3.
//   Region death:  buf0: A0@P1 B0@P1 B1@P2 A1@P3;  buf1: +4 phases.
//   Stage ledger (all >=1 barrier-phase after last read of old content):
//     P1: buf1.A1<-kt(2i+1)  P2: buf1.B1<-kt(2i+1)
//     P3: buf0.A0<-kt(2i+2)  P4: buf0.B0<-kt(2i+2)  [vmcnt(4)]
//     P5: buf0.A1<-kt(2i+2)  P6: buf0.B1<-kt(2i+2)
//     P7: buf1.A0<-kt(2i+3)  P8: buf1.B0<-kt(2i+3)  [vmcnt(4)]
//   vmcnt(4) before the trailing barrier of P4/P8 certifies: every wave's
//   loads older than its last 2 stage-phases have landed -> all regions a
//   phase reads were staged >=3 stage-phases before the covering wait. Never
//   vmcnt(0) in the loop (T3+T4); setprio(1) around MFMA clusters (T5).
// ---------------------------------------------------------------------------
#define BKT 64

#define BARR do { asm volatile("" ::: "memory"); __builtin_amdgcn_s_barrier(); asm volatile("" ::: "memory"); } while (0)
#define VMW4 asm volatile("s_waitcnt vmcnt(4)" ::: "memory")

#define RD_A(BUF, MQ) do { \
  _Pragma("unroll") for (int mp = 0; mp < 4; ++mp) { \
    af[mp][0] = *(const short8*)(lds + (BUF)*32768 + (MQ)*8192 + mp*1024 + aoff0); \
    af[mp][1] = *(const short8*)(lds + (BUF)*32768 + (MQ)*8192 + mp*1024 + aoff1); } } while (0)

#define RD_B(DST, BUF, NQ) do { \
  _Pragma("unroll") for (int np = 0; np < 2; ++np) { \
    DST[np][0] = *(const short8*)(lds + (BUF)*32768 + 16384 + (NQ)*8192 + np*1024 + boff0); \
    DST[np][1] = *(const short8*)(lds + (BUF)*32768 + 16384 + (NQ)*8192 + np*1024 + boff1); } } while (0)

#define ST_A(BUF, MQ, K0) do { \
  _Pragma("unroll") for (int c = 0; c < 2; ++c) \
    __builtin_amdgcn_global_load_lds( \
      (const __attribute__((address_space(1))) unsigned*)(As0 + (size_t)(c*128 + (MQ)*64) * D_IN + (K0)), \
      (__attribute__((address_space(3))) unsigned*)(ldsw + (BUF)*32768 + (MQ)*8192 + c*4096), 16, 0, 0); } while (0)

#define ST_B(BUF, NQ, K0) do { \
  _Pragma("unroll") for (int c = 0; c < 2; ++c) \
    __builtin_amdgcn_global_load_lds( \
      (const __attribute__((address_space(1))) unsigned*)(Bs0 + (size_t)(c*128 + (NQ)*32) * D_IN + (K0)), \
      (__attribute__((address_space(3))) unsigned*)(ldsw + (BUF)*32768 + 16384 + (NQ)*8192 + c*4096), 16, 0, 0); } while (0)

#define MM(MQ, NQ, BB) do { \
  _Pragma("unroll") for (int mp = 0; mp < 4; ++mp) \
  _Pragma("unroll") for (int np = 0; np < 2; ++np) { \
    acc[(MQ)*4+mp][(NQ)*2+np] = __builtin_amdgcn_mfma_f32_16x16x32_bf16( \
        af[mp][0], BB[np][0], acc[(MQ)*4+mp][(NQ)*2+np], 0, 0, 0); \
    acc[(MQ)*4+mp][(NQ)*2+np] = __builtin_amdgcn_mfma_f32_16x16x32_bf16( \
        af[mp][1], BB[np][1], acc[(MQ)*4+mp][(NQ)*2+np], 0, 0, 0); } } while (0)

#define PH(MMCALL) do { BARR; __builtin_amdgcn_s_setprio(1); \
  __builtin_amdgcn_sched_barrier(0); MMCALL; __builtin_amdgcn_sched_barrier(0); \
  __builtin_amdgcn_s_setprio(0); BARR; } while (0)

#define PHV(MMCALL) do { BARR; __builtin_amdgcn_s_setprio(1); \
  __builtin_amdgcn_sched_barrier(0); MMCALL; __builtin_amdgcn_sched_barrier(0); \
  __builtin_amdgcn_s_setprio(0); VMW4; BARR; } while (0)

__global__ __launch_bounds__(512, 2) void encode_mfma256(
    const ushort_t* __restrict__ A,    // [chunkM, D_IN] bf16 bits (x)
    const ushort_t* __restrict__ B,    // [D_HID, D_IN] bf16 bits (W)
    const float* __restrict__ bias,    // [D_HID]
    ushort_t* __restrict__ Y)          // [chunkM, D_HID] bf16 bits
{
    __shared__ ushort_t lds[65536] __attribute__((aligned(16)));  // 128 KB

    const int tid = threadIdx.x;
    const int wid = tid >> 6;          // 0..7
    const int ln  = tid & 63;
    const int wm  = wid >> 2;          // 0..1
    const int wn  = wid & 3;           // 0..3

    // XCD-aware block swizzle (gridDim.x = 64*Mtiles, always % 8 == 0)
    const int nwg = gridDim.x;
    const int cpx = nwg >> 3;
    const int swz = ((int)blockIdx.x & 7) * cpx + ((int)blockIdx.x >> 3);
    const int tileM = (swz >> 6) * 256;
    const int tileN = (swz & 63) * 256;

    // fragment read offsets (halfwords, region-local, swizzled)
    const int fcol = ln & 15;
    const int khi  = (ln >> 4) << 3;           // 0,8,16,24
    const int swzk = (fcol & 7) << 3;
    const int aoff0 = (wm*64 + fcol)*64 + ((khi)      ^ swzk);
    const int aoff1 = (wm*64 + fcol)*64 + ((32 + khi) ^ swzk);
    const int boff0 = (wn*32 + fcol)*64 + ((khi)      ^ swzk);
    const int boff1 = (wn*32 + fcol)*64 + ((32 + khi) ^ swzk);

    // staging: thread covers phys halfwords [tid*8 + c*4096, +8) of a region;
    // row i = (tid>>3) + c*64, pre-swizzled logical k = 8*((tid&7)^(i&7))
    const int r8   = tid >> 3;                 // 0..63
    const int klog = ((tid & 7) ^ (r8 & 7)) << 3;
    const ushort_t* As0 = A + (size_t)(tileM + r8) * D_IN + klog;
    const ushort_t* Bs0 = B + (size_t)(tileN + ((r8 >> 5) << 6) + (r8 & 31)) * D_IN + klog;
    ushort_t* ldsw = lds + wid * 512;          // wave-uniform base (HW adds lane*16B)

    floatx4 acc[8][4] = {};
    short8 af[4][2], bq0[2][2], bq1[2][2];

    // prologue: kt0 -> buf0 (all 4 regions), kt1 -> buf1 (A0,B0); 12 loads
    ST_A(0, 0, 0); ST_A(0, 1, 0); ST_B(0, 0, 0); ST_B(0, 1, 0);
    ST_A(1, 0, BKT); ST_B(1, 0, BKT);
    VMW4;           // kt0's 8 loads landed (newest 4 = kt1's A0,B0)
    BARR;

    for (int it = 0; it < 16; ++it) {
        const int kOdd = (2*it + 1) * BKT;            // kt(2i+1), always valid
        const int kE2  = ((2*it + 2) & 31) * BKT;     // kt(2i+2), wraps on tail
        const int kO2  = ((2*it + 3) & 31) * BKT;     // kt(2i+3), wraps on tail

        // P1: quadrant (0,0) of buf0
        RD_A(0, 0); RD_B(bq0, 0, 0);
        ST_A(1, 1, kOdd);
        PH(MM(0, 0, bq0));
        // P2: (0,1) — A regs reused
        RD_B(bq1, 0, 1);
        ST_B(1, 1, kOdd);
        PH(MM(0, 1, bq1));
        // P3: (1,0) — B0 regs reused
        RD_A(0, 1);
        ST_A(0, 0, kE2);
        PH(MM(1, 0, bq0));
        // P4: (1,1) — no ds_reads
        ST_B(0, 0, kE2);
        PHV(MM(1, 1, bq1));
        // P5: quadrant (0,0) of buf1
        RD_A(1, 0); RD_B(bq0, 1, 0);
        ST_A(0, 1, kE2);
        PH(MM(0, 0, bq0));
        // P6
        RD_B(bq1, 1, 1);
        ST_B(0, 1, kE2);
        PH(MM(0, 1, bq1));
        // P7
        RD_A(1, 1);
        ST_A(1, 0, kO2);
        PH(MM(1, 0, bq0));
        // P8
        ST_B(1, 0, kO2);
        PHV(MM(1, 1, bq1));
    }

    // epilogue: C/D layout col=lane&15, row=(lane>>4)*4+reg
    const int orow = (ln >> 4) * 4;
#pragma unroll
    for (int n = 0; n < 4; ++n) {
        const int gcol = tileN + wn * 64 + n * 16 + fcol;
        const float bc = bias[gcol];
#pragma unroll
        for (int m = 0; m < 8; ++m) {
            const int grow = tileM + wm * 128 + m * 16 + orow;
#pragma unroll
            for (int r = 0; r < 4; ++r)
                Y[(size_t)(grow + r) * D_HID + gcol] = f2bf(acc[m][n][r] + bc);
        }
    }
}

// ---------------------------------------------------------------------------
// Histogram threshold select on bf16 y: emit UNORDERED superset of the
// top-TARGET coarse elements per row (exact ranking by refine_kernel).
// key16 = monotonic 16-bit transform of bf16 bits.
// ---------------------------------------------------------------------------
__device__ __forceinline__ unsigned bf2key(unsigned u) {
    return (u & 0x8000u) ? (~u & 0xFFFFu) : (u | 0x8000u);
}

__global__ __launch_bounds__(256) void topk_select(
    const ushort_t* __restrict__ y,    // [chunkM, D_HID] bf16
    int* __restrict__ cand,            // [BATCH, CBUF]
    int* __restrict__ ccount,          // [BATCH]
    int rowBase)
{
    __shared__ unsigned hist[NBINS];   // 16 KB
    __shared__ unsigned psuf[257];
    __shared__ int sBstar;
    __shared__ unsigned scnt;

    const int tid = threadIdx.x;
    const int row = rowBase + blockIdx.x;
    const short8* yr8 = (const short8*)(y + (size_t)blockIdx.x * D_HID);

    for (int i = tid; i < NBINS; i += 256) hist[i] = 0;
    if (tid == 0) { sBstar = 0; scnt = 0; }
    __syncthreads();

    // Pass 1: histogram of key16 >> 4
    for (int j = 0; j < 8; ++j) {
        union { short8 v; ushort_t u[8]; } p;
        p.v = yr8[tid + j * 256];
#pragma unroll
        for (int c = 0; c < 8; ++c)
            atomicAdd(&hist[bf2key(p.u[c]) >> 4], 1u);
    }
    __syncthreads();

    {
        unsigned s = 0;
#pragma unroll
        for (int i = 0; i < 16; ++i) s += hist[tid * 16 + i];
        psuf[tid] = s;
    }
    __syncthreads();
    if (tid == 0) {
        unsigned run = 0;
        for (int t = 255; t >= 0; --t) { run += psuf[t]; psuf[t] = run; }
        psuf[256] = 0;
    }
    __syncthreads();
    {
        unsigned run = psuf[tid + 1];
        for (int b = tid * 16 + 15; b >= tid * 16; --b) {
            run += hist[b];
            if (run >= TARGET) { atomicMax(&sBstar, b); break; }
        }
    }
    __syncthreads();
    const unsigned keyT = ((unsigned)sBstar) << 4;

    // Pass 2: compact candidate indices (unordered)
    for (int j = 0; j < 8; ++j) {
        const int i8 = tid + j * 256;
        union { short8 v; ushort_t u[8]; } p;
        p.v = yr8[i8];
#pragma unroll
        for (int c = 0; c < 8; ++c) {
            if (bf2key(p.u[c]) >= keyT) {
                unsigned pos = atomicAdd(&scnt, 1u);
                if (pos < CBUF) cand[(size_t)row * CBUF + pos] = i8 * 8 + c;
            }
        }
    }
    __syncthreads();
    if (tid == 0) ccount[row] = (int)min(scnt, (unsigned)CBUF);
}

// ---------------------------------------------------------------------------
// fp64 refinement on the ORIGINAL fp32 inputs: recompute candidate dot
// products exactly, rank (value desc, idx asc), emit top-16 vals + idxs.
// (v2 MLP restructure: x row in registers, 8 unrolled float4 W loads,
//  4 independent fp64 accumulators, wave-level shfl argmax.)
// ---------------------------------------------------------------------------
__global__ __launch_bounds__(256, 4) void refine_kernel(
    const float* __restrict__ x,       // [BATCH, D_IN]
    const float* __restrict__ W,       // [D_HID, D_IN]
    const float* __restrict__ bias,    // [D_HID]
    const int* __restrict__ cand,      // [BATCH, CBUF]
    const int* __restrict__ ccount,    // [BATCH]
    float* __restrict__ vals,          // [BATCH, TOPK]
    int* __restrict__ idxs)            // [BATCH, TOPK]
{
    __shared__ double sdot[CBUF];      // 4 KB
    __shared__ int    sidx[CBUF];      // 2 KB
    __shared__ double rdv[4];
    __shared__ int    rdc[4];

    const int b = blockIdx.x;
    const int tid = threadIdx.x;
    const int C = ccount[b];

    for (int c = tid; c < C; c += 256) sidx[c] = cand[(size_t)b * CBUF + c];
    __syncthreads();

    const int wave = tid >> 6;
    const int lane = tid & 63;

    // x-row slices for this lane: same for every candidate -> registers.
    const float4* xg4 = (const float4*)(x + (size_t)b * D_IN);
    float4 xr[8];
#pragma unroll
    for (int i = 0; i < 8; ++i) xr[i] = xg4[lane + i * 64];

    for (int c = wave; c < C; c += 4) {
        const int h = sidx[c];
        const float4* wr4 = (const float4*)(W + (size_t)h * D_IN);
        const float bh = bias[h];
        double a0 = 0.0, a1 = 0.0, a2 = 0.0, a3 = 0.0;
#pragma unroll
        for (int i = 0; i < 8; ++i) {
            float4 w = wr4[lane + i * 64];
            a0 += (double)xr[i].x * (double)w.x;
            a1 += (double)xr[i].y * (double)w.y;
            a2 += (double)xr[i].z * (double)w.z;
            a3 += (double)xr[i].w * (double)w.w;
        }
        double acc = (a0 + a1) + (a2 + a3);
#pragma unroll
        for (int off = 32; off > 0; off >>= 1)
            acc += __shfl_down(acc, off, 64);
        if (lane == 0) sdot[c] = acc + (double)bh;
    }
    __syncthreads();

    for (int k = 0; k < TOPK; ++k) {
        double bv = -1.0e300; int bc = -1;
        for (int c = tid; c < C; c += 256) {
            double v = sdot[c];
            if (v > bv || (v == bv && bc >= 0 && sidx[c] < sidx[bc])) {
                bv = v; bc = c;
            }
        }
#pragma unroll
        for (int off = 32; off > 0; off >>= 1) {
            double v2 = __shfl_down(bv, off, 64);
            int    c2 = __shfl_down(bc, off, 64);
            bool better = (v2 > bv) ||
                (v2 == bv && c2 >= 0 &&
                 (bc < 0 || sidx[c2] < sidx[bc]));
            if (better) { bv = v2; bc = c2; }
        }
        if (lane == 0) { rdv[wave] = bv; rdc[wave] = bc; }
        __syncthreads();
        if (tid == 0) {
            double fv = rdv[0]; int fc = rdc[0];
#pragma unroll
            for (int w = 1; w < 4; ++w) {
                double v2 = rdv[w]; int c2 = rdc[w];
                bool better = (v2 > fv) ||
                    (v2 == fv && c2 >= 0 &&
                     (fc < 0 || sidx[c2] < sidx[fc]));
                if (better) { fv = v2; fc = c2; }
            }
            vals[(size_t)b * TOPK + k] = (float)fv;
            idxs[(size_t)b * TOPK + k] = sidx[fc];
            sdot[fc] = -1.0e300;
        }
        __syncthreads();
    }
}

// ---------------------------------------------------------------------------
// Decode: out[b, :] = sum_k vals[b,k] * W[idx[b,k], :]  (W = w_enc_w, fp32)
// Also writes idx as float into the second output region.
// ---------------------------------------------------------------------------
__global__ __launch_bounds__(256) void decode_kernel(
    const float* __restrict__ vals,
    const int* __restrict__ idxs,
    const float* __restrict__ W,       // [D_HID, D_IN]
    float* __restrict__ out,           // [BATCH, D_IN]
    float* __restrict__ idxOut)        // [BATCH, TOPK] as float
{
    __shared__ float sv[TOPK];
    __shared__ int   si[TOPK];
    const int b = blockIdx.x;
    const int tid = threadIdx.x;

    if (tid < TOPK) {
        float vv = vals[(size_t)b * TOPK + tid];
        int   ii = idxs[(size_t)b * TOPK + tid];
        sv[tid] = vv; si[tid] = ii;
        idxOut[(size_t)b * TOPK + tid] = (float)ii;
    }
    __syncthreads();

    const float4* W4 = (const float4*)W;
    float4* out4 = (float4*)(out + (size_t)b * D_IN);
    for (int d4 = tid; d4 < D_IN / 4; d4 += 256) {
        float4 acc = {0.f, 0.f, 0.f, 0.f};
#pragma unroll
        for (int k = 0; k < TOPK; ++k) {
            float4 w = W4[(size_t)si[k] * (D_IN / 4) + d4];
            float s = sv[k];
            acc.x += s * w.x; acc.y += s * w.y;
            acc.z += s * w.z; acc.w += s * w.w;
        }
        out4[d4] = acc;
    }
}

// ---------------------------------------------------------------------------
extern "C" void kernel_launch(void* const* d_in, const int* in_sizes, int n_in,
                              void* d_out, int out_size, void* d_ws, size_t ws_size,
                              hipStream_t stream)
{
    const float* x    = (const float*)d_in[0];  // [BATCH, D_IN]
    const float* Wenc = (const float*)d_in[1];  // [D_HID, D_IN]
    const float* bias = (const float*)d_in[2];  // [D_HID]
    // d_in[3] = w_emb_w — mathematically Wenc^T, unused.

    float* out    = (float*)d_out;                   // [BATCH, D_IN] fp32
    float* idxOut = out + (size_t)BATCH * D_IN;      // [BATCH, TOPK] as fp32

    char* ws = (char*)d_ws;
    size_t off = 0;
    int*      cand   = (int*)(ws + off);      off += (size_t)BATCH * CBUF * 4;   // 8 MB
    int*      ccount = (int*)(ws + off);      off += (size_t)BATCH * 4;
    float*    vals   = (float*)(ws + off);    off += (size_t)BATCH * TOPK * 4;
    int*      idxs   = (int*)(ws + off);      off += (size_t)BATCH * TOPK * 4;
    off = (off + 255) & ~(size_t)255;
    ushort_t* xbf    = (ushort_t*)(ws + off); off += (size_t)BATCH * D_IN * 2;   // 16 MB
    ushort_t* wbf    = (ushort_t*)(ws + off); off += (size_t)D_HID * D_IN * 2;   // 64 MB
    const size_t head = (off + 255) & ~(size_t)255;
    ushort_t* ybf = (ushort_t*)(ws + head);

    int chunk = BATCH;
    while (chunk > 256 && head + (size_t)chunk * D_HID * 2 > ws_size) chunk >>= 1;

    const int nx8 = BATCH * D_IN / 8;       // 1,048,576
    const int nw8 = D_HID * D_IN / 8;       // 4,194,304
    convert_bf16<<<(nx8 + 255) / 256, 256, 0, stream>>>(x, xbf, nx8);
    convert_bf16<<<(nw8 + 255) / 256, 256, 0, stream>>>(Wenc, wbf, nw8);

    for (int r0 = 0; r0 < BATCH; r0 += chunk) {
        const int mtiles = chunk / 256;
        encode_mfma256<<<64 * mtiles, 512, 0, stream>>>(
            xbf + (size_t)r0 * D_IN, wbf, bias, ybf);
        topk_select<<<chunk, 256, 0, stream>>>(ybf, cand, ccount, r0);
    }
    refine_kernel<<<BATCH, 256, 0, stream>>>(x, Wenc, bias, cand, ccount, vals, idxs);
    decode_kernel<<<BATCH, 256, 0, stream>>>(vals, idxs, Wenc, out, idxOut);
}

// Round 3
// 924.267 us; speedup vs baseline: 1.2922x; 1.0280x over previous
//
#include <hip/hip_runtime.h>
#include <cfloat>
#include <cstdint>

#define D_IN  2048
#define D_HID 16384
#define TOPK  16
#define BATCH 4096

#define NBINS    4096      // 12-bit histogram: sign + 8 exp + 3 mantissa bits
#define CBUF     512       // candidate cap per row
#define TARGET   32        // min candidates above threshold (margin over 16)

typedef unsigned short ushort_t;
typedef __attribute__((ext_vector_type(8))) short short8;
typedef __attribute__((ext_vector_type(4))) float floatx4;

// ---------------------------------------------------------------------------
// fp32 -> bf16 (RNE) conversion, 8 elements/thread, 16B stores
// ---------------------------------------------------------------------------
__device__ __forceinline__ ushort_t f2bf(float f) {
    unsigned u = __float_as_uint(f);
    u = (u + 0x7FFFu + ((u >> 16) & 1u)) >> 16;
    return (ushort_t)u;
}

__global__ __launch_bounds__(256) void convert_bf16(
    const float* __restrict__ src, ushort_t* __restrict__ dst, int n8)
{
    const int i = blockIdx.x * 256 + threadIdx.x;
    if (i >= n8) return;
    const float4* s4 = (const float4*)src;
    float4 a = s4[2 * i];
    float4 b = s4[2 * i + 1];
    union { ushort_t u[8]; short8 v; } p;
    p.u[0] = f2bf(a.x); p.u[1] = f2bf(a.y); p.u[2] = f2bf(a.z); p.u[3] = f2bf(a.w);
    p.u[4] = f2bf(b.x); p.u[5] = f2bf(b.y); p.u[6] = f2bf(b.z); p.u[7] = f2bf(b.w);
    *(short8*)(dst + (size_t)i * 8) = p.v;
}

// ---------------------------------------------------------------------------
// Coarse encode GEMM, bf16 MFMA — 256x256 8-phase template (m201 structure):
//   BM=BN=256, BK=64, 8 waves (2M x 4N), per-wave output 128x64,
//   LDS 128 KB = 2 bufs x {A0,A1,B0,B1} regions of 16 KB,
//   XOR bank swizzle both-sides; counted vmcnt(4), never 0 in loop;
//   setprio(1) around MFMA clusters.  (verified round 2: 3.36e7 bank
//   conflicts -> gone from top-5, encode ~350 -> ~200 us)
// ---------------------------------------------------------------------------
#define BKT 64

#define BARR do { asm volatile("" ::: "memory"); __builtin_amdgcn_s_barrier(); asm volatile("" ::: "memory"); } while (0)
#define VMW4 asm volatile("s_waitcnt vmcnt(4)" ::: "memory")

#define RD_A(BUF, MQ) do { \
  _Pragma("unroll") for (int mp = 0; mp < 4; ++mp) { \
    af[mp][0] = *(const short8*)(lds + (BUF)*32768 + (MQ)*8192 + mp*1024 + aoff0); \
    af[mp][1] = *(const short8*)(lds + (BUF)*32768 + (MQ)*8192 + mp*1024 + aoff1); } } while (0)

#define RD_B(DST, BUF, NQ) do { \
  _Pragma("unroll") for (int np = 0; np < 2; ++np) { \
    DST[np][0] = *(const short8*)(lds + (BUF)*32768 + 16384 + (NQ)*8192 + np*1024 + boff0); \
    DST[np][1] = *(const short8*)(lds + (BUF)*32768 + 16384 + (NQ)*8192 + np*1024 + boff1); } } while (0)

#define ST_A(BUF, MQ, K0) do { \
  _Pragma("unroll") for (int c = 0; c < 2; ++c) \
    __builtin_amdgcn_global_load_lds( \
      (const __attribute__((address_space(1))) unsigned*)(As0 + (size_t)(c*128 + (MQ)*64) * D_IN + (K0)), \
      (__attribute__((address_space(3))) unsigned*)(ldsw + (BUF)*32768 + (MQ)*8192 + c*4096), 16, 0, 0); } while (0)

#define ST_B(BUF, NQ, K0) do { \
  _Pragma("unroll") for (int c = 0; c < 2; ++c) \
    __builtin_amdgcn_global_load_lds( \
      (const __attribute__((address_space(1))) unsigned*)(Bs0 + (size_t)(c*128 + (NQ)*32) * D_IN + (K0)), \
      (__attribute__((address_space(3))) unsigned*)(ldsw + (BUF)*32768 + 16384 + (NQ)*8192 + c*4096), 16, 0, 0); } while (0)

#define MM(MQ, NQ, BB) do { \
  _Pragma("unroll") for (int mp = 0; mp < 4; ++mp) \
  _Pragma("unroll") for (int np = 0; np < 2; ++np) { \
    acc[(MQ)*4+mp][(NQ)*2+np] = __builtin_amdgcn_mfma_f32_16x16x32_bf16( \
        af[mp][0], BB[np][0], acc[(MQ)*4+mp][(NQ)*2+np], 0, 0, 0); \
    acc[(MQ)*4+mp][(NQ)*2+np] = __builtin_amdgcn_mfma_f32_16x16x32_bf16( \
        af[mp][1], BB[np][1], acc[(MQ)*4+mp][(NQ)*2+np], 0, 0, 0); } } while (0)

#define PH(MMCALL) do { BARR; __builtin_amdgcn_s_setprio(1); \
  __builtin_amdgcn_sched_barrier(0); MMCALL; __builtin_amdgcn_sched_barrier(0); \
  __builtin_amdgcn_s_setprio(0); BARR; } while (0)

#define PHV(MMCALL) do { BARR; __builtin_amdgcn_s_setprio(1); \
  __builtin_amdgcn_sched_barrier(0); MMCALL; __builtin_amdgcn_sched_barrier(0); \
  __builtin_amdgcn_s_setprio(0); VMW4; BARR; } while (0)

__global__ __launch_bounds__(512, 2) void encode_mfma256(
    const ushort_t* __restrict__ A,    // [chunkM, D_IN] bf16 bits (x)
    const ushort_t* __restrict__ B,    // [D_HID, D_IN] bf16 bits (W)
    const float* __restrict__ bias,    // [D_HID]
    ushort_t* __restrict__ Y)          // [chunkM, D_HID] bf16 bits
{
    __shared__ ushort_t lds[65536] __attribute__((aligned(16)));  // 128 KB

    const int tid = threadIdx.x;
    const int wid = tid >> 6;          // 0..7
    const int ln  = tid & 63;
    const int wm  = wid >> 2;          // 0..1
    const int wn  = wid & 3;           // 0..3

    // XCD-aware block swizzle (gridDim.x = 64*Mtiles, always % 8 == 0)
    const int nwg = gridDim.x;
    const int cpx = nwg >> 3;
    const int swz = ((int)blockIdx.x & 7) * cpx + ((int)blockIdx.x >> 3);
    const int tileM = (swz >> 6) * 256;
    const int tileN = (swz & 63) * 256;

    // fragment read offsets (halfwords, region-local, swizzled)
    const int fcol = ln & 15;
    const int khi  = (ln >> 4) << 3;           // 0,8,16,24
    const int swzk = (fcol & 7) << 3;
    const int aoff0 = (wm*64 + fcol)*64 + ((khi)      ^ swzk);
    const int aoff1 = (wm*64 + fcol)*64 + ((32 + khi) ^ swzk);
    const int boff0 = (wn*32 + fcol)*64 + ((khi)      ^ swzk);
    const int boff1 = (wn*32 + fcol)*64 + ((32 + khi) ^ swzk);

    // staging: thread covers phys halfwords [tid*8 + c*4096, +8) of a region;
    // row i = (tid>>3) + c*64, pre-swizzled logical k = 8*((tid&7)^(i&7))
    const int r8   = tid >> 3;                 // 0..63
    const int klog = ((tid & 7) ^ (r8 & 7)) << 3;
    const ushort_t* As0 = A + (size_t)(tileM + r8) * D_IN + klog;
    const ushort_t* Bs0 = B + (size_t)(tileN + ((r8 >> 5) << 6) + (r8 & 31)) * D_IN + klog;
    ushort_t* ldsw = lds + wid * 512;          // wave-uniform base (HW adds lane*16B)

    floatx4 acc[8][4] = {};
    short8 af[4][2], bq0[2][2], bq1[2][2];

    // prologue: kt0 -> buf0 (all 4 regions), kt1 -> buf1 (A0,B0); 12 loads
    ST_A(0, 0, 0); ST_A(0, 1, 0); ST_B(0, 0, 0); ST_B(0, 1, 0);
    ST_A(1, 0, BKT); ST_B(1, 0, BKT);
    VMW4;           // kt0's 8 loads landed (newest 4 = kt1's A0,B0)
    BARR;

    for (int it = 0; it < 16; ++it) {
        const int kOdd = (2*it + 1) * BKT;            // kt(2i+1), always valid
        const int kE2  = ((2*it + 2) & 31) * BKT;     // kt(2i+2), wraps on tail
        const int kO2  = ((2*it + 3) & 31) * BKT;     // kt(2i+3), wraps on tail

        // P1: quadrant (0,0) of buf0
        RD_A(0, 0); RD_B(bq0, 0, 0);
        ST_A(1, 1, kOdd);
        PH(MM(0, 0, bq0));
        // P2: (0,1) — A regs reused
        RD_B(bq1, 0, 1);
        ST_B(1, 1, kOdd);
        PH(MM(0, 1, bq1));
        // P3: (1,0) — B0 regs reused
        RD_A(0, 1);
        ST_A(0, 0, kE2);
        PH(MM(1, 0, bq0));
        // P4: (1,1) — no ds_reads
        ST_B(0, 0, kE2);
        PHV(MM(1, 1, bq1));
        // P5: quadrant (0,0) of buf1
        RD_A(1, 0); RD_B(bq0, 1, 0);
        ST_A(0, 1, kE2);
        PH(MM(0, 0, bq0));
        // P6
        RD_B(bq1, 1, 1);
        ST_B(0, 1, kE2);
        PH(MM(0, 1, bq1));
        // P7
        RD_A(1, 1);
        ST_A(1, 0, kO2);
        PH(MM(1, 0, bq0));
        // P8
        ST_B(1, 0, kO2);
        PHV(MM(1, 1, bq1));
    }

    // epilogue: C/D layout col=lane&15, row=(lane>>4)*4+reg
    const int orow = (ln >> 4) * 4;
#pragma unroll
    for (int n = 0; n < 4; ++n) {
        const int gcol = tileN + wn * 64 + n * 16 + fcol;
        const float bc = bias[gcol];
#pragma unroll
        for (int m = 0; m < 8; ++m) {
            const int grow = tileM + wm * 128 + m * 16 + orow;
#pragma unroll
            for (int r = 0; r < 4; ++r)
                Y[(size_t)(grow + r) * D_HID + gcol] = f2bf(acc[m][n][r] + bc);
        }
    }
}

// ---------------------------------------------------------------------------
// Histogram threshold select on bf16 y: emit UNORDERED superset of the
// top-TARGET coarse elements per row (exact ranking by refine_decode).
// key16 = monotonic 16-bit transform of bf16 bits.
// ---------------------------------------------------------------------------
__device__ __forceinline__ unsigned bf2key(unsigned u) {
    return (u & 0x8000u) ? (~u & 0xFFFFu) : (u | 0x8000u);
}

__global__ __launch_bounds__(256) void topk_select(
    const ushort_t* __restrict__ y,    // [chunkM, D_HID] bf16
    int* __restrict__ cand,            // [BATCH, CBUF]
    int* __restrict__ ccount,          // [BATCH]
    int rowBase)
{
    __shared__ unsigned hist[NBINS];   // 16 KB
    __shared__ unsigned psuf[257];
    __shared__ int sBstar;
    __shared__ unsigned scnt;

    const int tid = threadIdx.x;
    const int row = rowBase + blockIdx.x;
    const short8* yr8 = (const short8*)(y + (size_t)blockIdx.x * D_HID);

    for (int i = tid; i < NBINS; i += 256) hist[i] = 0;
    if (tid == 0) { sBstar = 0; scnt = 0; }
    __syncthreads();

    // Pass 1: histogram of key16 >> 4
    for (int j = 0; j < 8; ++j) {
        union { short8 v; ushort_t u[8]; } p;
        p.v = yr8[tid + j * 256];
#pragma unroll
        for (int c = 0; c < 8; ++c)
            atomicAdd(&hist[bf2key(p.u[c]) >> 4], 1u);
    }
    __syncthreads();

    {
        unsigned s = 0;
#pragma unroll
        for (int i = 0; i < 16; ++i) s += hist[tid * 16 + i];
        psuf[tid] = s;
    }
    __syncthreads();
    if (tid == 0) {
        unsigned run = 0;
        for (int t = 255; t >= 0; --t) { run += psuf[t]; psuf[t] = run; }
        psuf[256] = 0;
    }
    __syncthreads();
    {
        unsigned run = psuf[tid + 1];
        for (int b = tid * 16 + 15; b >= tid * 16; --b) {
            run += hist[b];
            if (run >= TARGET) { atomicMax(&sBstar, b); break; }
        }
    }
    __syncthreads();
    const unsigned keyT = ((unsigned)sBstar) << 4;

    // Pass 2: compact candidate indices (unordered)
    for (int j = 0; j < 8; ++j) {
        const int i8 = tid + j * 256;
        union { short8 v; ushort_t u[8]; } p;
        p.v = yr8[i8];
#pragma unroll
        for (int c = 0; c < 8; ++c) {
            if (bf2key(p.u[c]) >= keyT) {
                unsigned pos = atomicAdd(&scnt, 1u);
                if (pos < CBUF) cand[(size_t)row * CBUF + pos] = i8 * 8 + c;
            }
        }
    }
    __syncthreads();
    if (tid == 0) ccount[row] = (int)min(scnt, (unsigned)CBUF);
}

// ---------------------------------------------------------------------------
// Fused fp64 refinement + decode.
//
// v3: round-2 showed VGPR_Count=56 -> the 8 float4 W loads were NOT hoisted
// (xr alone is 32 VGPR); inner loop was a serial load->FMA chain + a serial
// 6-level fp64 shfl reduce.  Now:
//   - __launch_bounds__(256,3) (<=168 VGPR) instead of (256,4)
//   - 2 candidates per iteration, 16 explicit float4 loads staged before
//     any FMA (16 KB/wave in flight)
//   - the two fp64 shfl-reduce chains interleaved (ILP=2 on ds_bpermute)
//   - decode fused at the end: the top-16 W rows were just read by this
//     block (L2/L3-warm); write out + idxOut here, no separate kernel.
// ---------------------------------------------------------------------------
__global__ __launch_bounds__(256, 3) void refine_decode(
    const float* __restrict__ x,       // [BATCH, D_IN]
    const float* __restrict__ W,       // [D_HID, D_IN]
    const float* __restrict__ bias,    // [D_HID]
    const int* __restrict__ cand,      // [BATCH, CBUF]
    const int* __restrict__ ccount,    // [BATCH]
    float* __restrict__ out,           // [BATCH, D_IN]
    float* __restrict__ idxOut)        // [BATCH, TOPK] as float
{
    __shared__ double sdot[CBUF];      // 4 KB
    __shared__ int    sidx[CBUF];      // 2 KB
    __shared__ double rdv[4];
    __shared__ int    rdc[4];
    __shared__ float  ssv[TOPK];
    __shared__ int    ssi[TOPK];

    const int b = blockIdx.x;
    const int tid = threadIdx.x;
    const int C = ccount[b];

    for (int c = tid; c < C; c += 256) sidx[c] = cand[(size_t)b * CBUF + c];
    __syncthreads();

    const int wave = tid >> 6;
    const int lane = tid & 63;

    // x-row slices for this lane: same for every candidate -> registers.
    const float4* xg4 = (const float4*)(x + (size_t)b * D_IN);
    float4 xr[8];
#pragma unroll
    for (int i = 0; i < 8; ++i) xr[i] = xg4[lane + i * 64];

    // phase 1: exact fp64 dots, 2 candidates per iteration
    for (int c0 = wave; c0 < C; c0 += 8) {
        const int c1 = c0 + 4;
        const bool has1 = (c1 < C);
        const int h0 = sidx[c0];
        const int h1 = has1 ? sidx[c1] : h0;
        const float4* p0 = (const float4*)(W + (size_t)h0 * D_IN) + lane;
        const float4* p1 = (const float4*)(W + (size_t)h1 * D_IN) + lane;
        const float bh0 = bias[h0];
        const float bh1 = bias[h1];

        // stage all 16 loads before any use
        float4 u0 = p0[0],   v0 = p1[0];
        float4 u1 = p0[64],  v1 = p1[64];
        float4 u2 = p0[128], v2 = p1[128];
        float4 u3 = p0[192], v3 = p1[192];
        float4 u4 = p0[256], v4 = p1[256];
        float4 u5 = p0[320], v5 = p1[320];
        float4 u6 = p0[384], v6 = p1[384];
        float4 u7 = p0[448], v7 = p1[448];

        double a0 = 0.0, a1 = 0.0, a2 = 0.0, a3 = 0.0;
        double e0 = 0.0, e1 = 0.0, e2 = 0.0, e3 = 0.0;
#define FMA2(UU, VV, II) \
        a0 += (double)xr[II].x * (double)UU.x; e0 += (double)xr[II].x * (double)VV.x; \
        a1 += (double)xr[II].y * (double)UU.y; e1 += (double)xr[II].y * (double)VV.y; \
        a2 += (double)xr[II].z * (double)UU.z; e2 += (double)xr[II].z * (double)VV.z; \
        a3 += (double)xr[II].w * (double)UU.w; e3 += (double)xr[II].w * (double)VV.w;
        FMA2(u0, v0, 0) FMA2(u1, v1, 1) FMA2(u2, v2, 2) FMA2(u3, v3, 3)
        FMA2(u4, v4, 4) FMA2(u5, v5, 5) FMA2(u6, v6, 6) FMA2(u7, v7, 7)
#undef FMA2

        double r0 = (a0 + a1) + (a2 + a3);
        double r1 = (e0 + e1) + (e2 + e3);
#pragma unroll
        for (int off = 32; off > 0; off >>= 1) {
            r0 += __shfl_down(r0, off, 64);
            r1 += __shfl_down(r1, off, 64);
        }
        if (lane == 0) {
            sdot[c0] = r0 + (double)bh0;
            if (has1) sdot[c1] = r1 + (double)bh1;
        }
    }
    __syncthreads();

    // phase 2: iterative top-16 (value desc, idx asc)
    for (int k = 0; k < TOPK; ++k) {
        double bv = -1.0e300; int bc = -1;
        for (int c = tid; c < C; c += 256) {
            double v = sdot[c];
            if (v > bv || (v == bv && bc >= 0 && sidx[c] < sidx[bc])) {
                bv = v; bc = c;
            }
        }
#pragma unroll
        for (int off = 32; off > 0; off >>= 1) {
            double v2 = __shfl_down(bv, off, 64);
            int    c2 = __shfl_down(bc, off, 64);
            bool better = (v2 > bv) ||
                (v2 == bv && c2 >= 0 &&
                 (bc < 0 || sidx[c2] < sidx[bc]));
            if (better) { bv = v2; bc = c2; }
        }
        if (lane == 0) { rdv[wave] = bv; rdc[wave] = bc; }
        __syncthreads();
        if (tid == 0) {
            double fv = rdv[0]; int fc = rdc[0];
#pragma unroll
            for (int w = 1; w < 4; ++w) {
                double v2 = rdv[w]; int c2 = rdc[w];
                bool better = (v2 > fv) ||
                    (v2 == fv && c2 >= 0 &&
                     (fc < 0 || sidx[c2] < sidx[fc]));
                if (better) { fv = v2; fc = c2; }
            }
            const int hsel = sidx[fc];
            ssv[k] = (float)fv;
            ssi[k] = hsel;
            idxOut[(size_t)b * TOPK + k] = (float)hsel;
            sdot[fc] = -1.0e300;
        }
        __syncthreads();
    }

    // phase 3: fused decode — rows are L2/L3-warm from phase 1
    const float4* W4 = (const float4*)W;
    float4* out4 = (float4*)(out + (size_t)b * D_IN);
#pragma unroll
    for (int d4 = tid; d4 < D_IN / 4; d4 += 256) {
        float4 acc = {0.f, 0.f, 0.f, 0.f};
#pragma unroll
        for (int k = 0; k < TOPK; ++k) {
            float4 w = W4[(size_t)ssi[k] * (D_IN / 4) + d4];
            float s = ssv[k];
            acc.x += s * w.x; acc.y += s * w.y;
            acc.z += s * w.z; acc.w += s * w.w;
        }
        out4[d4] = acc;
    }
}

// ---------------------------------------------------------------------------
extern "C" void kernel_launch(void* const* d_in, const int* in_sizes, int n_in,
                              void* d_out, int out_size, void* d_ws, size_t ws_size,
                              hipStream_t stream)
{
    const float* x    = (const float*)d_in[0];  // [BATCH, D_IN]
    const float* Wenc = (const float*)d_in[1];  // [D_HID, D_IN]
    const float* bias = (const float*)d_in[2];  // [D_HID]
    // d_in[3] = w_emb_w — mathematically Wenc^T, unused.

    float* out    = (float*)d_out;                   // [BATCH, D_IN] fp32
    float* idxOut = out + (size_t)BATCH * D_IN;      // [BATCH, TOPK] as fp32

    char* ws = (char*)d_ws;
    size_t off = 0;
    int*      cand   = (int*)(ws + off);      off += (size_t)BATCH * CBUF * 4;   // 8 MB
    int*      ccount = (int*)(ws + off);      off += (size_t)BATCH * 4;
    off = (off + 255) & ~(size_t)255;
    ushort_t* xbf    = (ushort_t*)(ws + off); off += (size_t)BATCH * D_IN * 2;   // 16 MB
    ushort_t* wbf    = (ushort_t*)(ws + off); off += (size_t)D_HID * D_IN * 2;   // 64 MB
    const size_t head = (off + 255) & ~(size_t)255;
    ushort_t* ybf = (ushort_t*)(ws + head);

    int chunk = BATCH;
    while (chunk > 256 && head + (size_t)chunk * D_HID * 2 > ws_size) chunk >>= 1;

    const int nx8 = BATCH * D_IN / 8;       // 1,048,576
    const int nw8 = D_HID * D_IN / 8;       // 4,194,304
    convert_bf16<<<(nx8 + 255) / 256, 256, 0, stream>>>(x, xbf, nx8);
    convert_bf16<<<(nw8 + 255) / 256, 256, 0, stream>>>(Wenc, wbf, nw8);

    for (int r0 = 0; r0 < BATCH; r0 += chunk) {
        const int mtiles = chunk / 256;
        encode_mfma256<<<64 * mtiles, 512, 0, stream>>>(
            xbf + (size_t)r0 * D_IN, wbf, bias, ybf);
        topk_select<<<chunk, 256, 0, stream>>>(ybf, cand, ccount, r0);
    }
    refine_decode<<<BATCH, 256, 0, stream>>>(x, Wenc, bias, cand, ccount, out, idxOut);
}

// Round 5
// 909.723 us; speedup vs baseline: 1.3128x; 1.0160x over previous
//
#include <hip/hip_runtime.h>
#include <cfloat>
#include <cstdint>

#define D_IN  2048
#define D_HID 16384
#define TOPK  16
#define BATCH 4096

#define NBINS    4096      // 12-bit histogram: sign + 8 exp + 3 mantissa bits
#define CBUF     512       // candidate cap per row
#define TARGET   16        // exact: bin of the 16th-largest coarse value
// threshold = (bin(16th) - 1) << 4: one full bin (~0.25 value units) of margin,
// >=10x the coarse-path error bound (~0.02).  (was TARGET=32, C~32-40 -> ~20)

typedef unsigned short ushort_t;
typedef __attribute__((ext_vector_type(8))) short short8;
typedef __attribute__((ext_vector_type(4))) float floatx4;

// ---------------------------------------------------------------------------
// fp32 -> bf16 (RNE) conversion, 8 elements/thread, 16B stores
// ---------------------------------------------------------------------------
__device__ __forceinline__ ushort_t f2bf(float f) {
    unsigned u = __float_as_uint(f);
    u = (u + 0x7FFFu + ((u >> 16) & 1u)) >> 16;
    return (ushort_t)u;
}

__global__ __launch_bounds__(256) void convert_bf16(
    const float* __restrict__ src, ushort_t* __restrict__ dst, int n8)
{
    const int i = blockIdx.x * 256 + threadIdx.x;
    if (i >= n8) return;
    const float4* s4 = (const float4*)src;
    float4 a = s4[2 * i];
    float4 b = s4[2 * i + 1];
    union { ushort_t u[8]; short8 v; } p;
    p.u[0] = f2bf(a.x); p.u[1] = f2bf(a.y); p.u[2] = f2bf(a.z); p.u[3] = f2bf(a.w);
    p.u[4] = f2bf(b.x); p.u[5] = f2bf(b.y); p.u[6] = f2bf(b.z); p.u[7] = f2bf(b.w);
    *(short8*)(dst + (size_t)i * 8) = p.v;
}

// ---------------------------------------------------------------------------
// Coarse encode GEMM, bf16 MFMA — 256x256 8-phase template (m201 structure):
//   BM=BN=256, BK=64, 8 waves (2M x 4N), per-wave output 128x64,
//   LDS 128 KB = 2 bufs x {A0,A1,B0,B1} regions of 16 KB,
//   XOR bank swizzle both-sides; counted vmcnt(4), never 0 in loop;
//   setprio(1) around MFMA clusters.  (verified round 2: 3.36e7 bank
//   conflicts -> gone from top-5, encode ~350 -> ~200 us)
// ---------------------------------------------------------------------------
#define BKT 64

#define BARR do { asm volatile("" ::: "memory"); __builtin_amdgcn_s_barrier(); asm volatile("" ::: "memory"); } while (0)
#define VMW4 asm volatile("s_waitcnt vmcnt(4)" ::: "memory")

#define RD_A(BUF, MQ) do { \
  _Pragma("unroll") for (int mp = 0; mp < 4; ++mp) { \
    af[mp][0] = *(const short8*)(lds + (BUF)*32768 + (MQ)*8192 + mp*1024 + aoff0); \
    af[mp][1] = *(const short8*)(lds + (BUF)*32768 + (MQ)*8192 + mp*1024 + aoff1); } } while (0)

#define RD_B(DST, BUF, NQ) do { \
  _Pragma("unroll") for (int np = 0; np < 2; ++np) { \
    DST[np][0] = *(const short8*)(lds + (BUF)*32768 + 16384 + (NQ)*8192 + np*1024 + boff0); \
    DST[np][1] = *(const short8*)(lds + (BUF)*32768 + 16384 + (NQ)*8192 + np*1024 + boff1); } } while (0)

#define ST_A(BUF, MQ, K0) do { \
  _Pragma("unroll") for (int c = 0; c < 2; ++c) \
    __builtin_amdgcn_global_load_lds( \
      (const __attribute__((address_space(1))) unsigned*)(As0 + (size_t)(c*128 + (MQ)*64) * D_IN + (K0)), \
      (__attribute__((address_space(3))) unsigned*)(ldsw + (BUF)*32768 + (MQ)*8192 + c*4096), 16, 0, 0); } while (0)

#define ST_B(BUF, NQ, K0) do { \
  _Pragma("unroll") for (int c = 0; c < 2; ++c) \
    __builtin_amdgcn_global_load_lds( \
      (const __attribute__((address_space(1))) unsigned*)(Bs0 + (size_t)(c*128 + (NQ)*32) * D_IN + (K0)), \
      (__attribute__((address_space(3))) unsigned*)(ldsw + (BUF)*32768 + 16384 + (NQ)*8192 + c*4096), 16, 0, 0); } while (0)

#define MM(MQ, NQ, BB) do { \
  _Pragma("unroll") for (int mp = 0; mp < 4; ++mp) \
  _Pragma("unroll") for (int np = 0; np < 2; ++np) { \
    acc[(MQ)*4+mp][(NQ)*2+np] = __builtin_amdgcn_mfma_f32_16x16x32_bf16( \
        af[mp][0], BB[np][0], acc[(MQ)*4+mp][(NQ)*2+np], 0, 0, 0); \
    acc[(MQ)*4+mp][(NQ)*2+np] = __builtin_amdgcn_mfma_f32_16x16x32_bf16( \
        af[mp][1], BB[np][1], acc[(MQ)*4+mp][(NQ)*2+np], 0, 0, 0); } } while (0)

#define PH(MMCALL) do { BARR; __builtin_amdgcn_s_setprio(1); \
  __builtin_amdgcn_sched_barrier(0); MMCALL; __builtin_amdgcn_sched_barrier(0); \
  __builtin_amdgcn_s_setprio(0); BARR; } while (0)

#define PHV(MMCALL) do { BARR; __builtin_amdgcn_s_setprio(1); \
  __builtin_amdgcn_sched_barrier(0); MMCALL; __builtin_amdgcn_sched_barrier(0); \
  __builtin_amdgcn_s_setprio(0); VMW4; BARR; } while (0)

__global__ __launch_bounds__(512, 2) void encode_mfma256(
    const ushort_t* __restrict__ A,    // [chunkM, D_IN] bf16 bits (x)
    const ushort_t* __restrict__ B,    // [D_HID, D_IN] bf16 bits (W)
    const float* __restrict__ bias,    // [D_HID]
    ushort_t* __restrict__ Y)          // [chunkM, D_HID] bf16 bits
{
    __shared__ ushort_t lds[65536] __attribute__((aligned(16)));  // 128 KB

    const int tid = threadIdx.x;
    const int wid = tid >> 6;          // 0..7
    const int ln  = tid & 63;
    const int wm  = wid >> 2;          // 0..1
    const int wn  = wid & 3;           // 0..3

    // XCD-aware block swizzle (gridDim.x = 64*Mtiles, always % 8 == 0)
    const int nwg = gridDim.x;
    const int cpx = nwg >> 3;
    const int swz = ((int)blockIdx.x & 7) * cpx + ((int)blockIdx.x >> 3);
    const int tileM = (swz >> 6) * 256;
    const int tileN = (swz & 63) * 256;

    // fragment read offsets (halfwords, region-local, swizzled)
    const int fcol = ln & 15;
    const int khi  = (ln >> 4) << 3;           // 0,8,16,24
    const int swzk = (fcol & 7) << 3;
    const int aoff0 = (wm*64 + fcol)*64 + ((khi)      ^ swzk);
    const int aoff1 = (wm*64 + fcol)*64 + ((32 + khi) ^ swzk);
    const int boff0 = (wn*32 + fcol)*64 + ((khi)      ^ swzk);
    const int boff1 = (wn*32 + fcol)*64 + ((32 + khi) ^ swzk);

    // staging: thread covers phys halfwords [tid*8 + c*4096, +8) of a region;
    // row i = (tid>>3) + c*64, pre-swizzled logical k = 8*((tid&7)^(i&7))
    const int r8   = tid >> 3;                 // 0..63
    const int klog = ((tid & 7) ^ (r8 & 7)) << 3;
    const ushort_t* As0 = A + (size_t)(tileM + r8) * D_IN + klog;
    const ushort_t* Bs0 = B + (size_t)(tileN + ((r8 >> 5) << 6) + (r8 & 31)) * D_IN + klog;
    ushort_t* ldsw = lds + wid * 512;          // wave-uniform base (HW adds lane*16B)

    floatx4 acc[8][4] = {};
    short8 af[4][2], bq0[2][2], bq1[2][2];

    // prologue: kt0 -> buf0 (all 4 regions), kt1 -> buf1 (A0,B0); 12 loads
    ST_A(0, 0, 0); ST_A(0, 1, 0); ST_B(0, 0, 0); ST_B(0, 1, 0);
    ST_A(1, 0, BKT); ST_B(1, 0, BKT);
    VMW4;           // kt0's 8 loads landed (newest 4 = kt1's A0,B0)
    BARR;

    for (int it = 0; it < 16; ++it) {
        const int kOdd = (2*it + 1) * BKT;            // kt(2i+1), always valid
        const int kE2  = ((2*it + 2) & 31) * BKT;     // kt(2i+2), wraps on tail
        const int kO2  = ((2*it + 3) & 31) * BKT;     // kt(2i+3), wraps on tail

        // P1: quadrant (0,0) of buf0
        RD_A(0, 0); RD_B(bq0, 0, 0);
        ST_A(1, 1, kOdd);
        PH(MM(0, 0, bq0));
        // P2: (0,1) — A regs reused
        RD_B(bq1, 0, 1);
        ST_B(1, 1, kOdd);
        PH(MM(0, 1, bq1));
        // P3: (1,0) — B0 regs reused
        RD_A(0, 1);
        ST_A(0, 0, kE2);
        PH(MM(1, 0, bq0));
        // P4: (1,1) — no ds_reads
        ST_B(0, 0, kE2);
        PHV(MM(1, 1, bq1));
        // P5: quadrant (0,0) of buf1
        RD_A(1, 0); RD_B(bq0, 1, 0);
        ST_A(0, 1, kE2);
        PH(MM(0, 0, bq0));
        // P6
        RD_B(bq1, 1, 1);
        ST_B(0, 1, kE2);
        PH(MM(0, 1, bq1));
        // P7
        RD_A(1, 1);
        ST_A(1, 0, kO2);
        PH(MM(1, 0, bq0));
        // P8
        ST_B(1, 0, kO2);
        PHV(MM(1, 1, bq1));
    }

    // epilogue: C/D layout col=lane&15, row=(lane>>4)*4+reg
    const int orow = (ln >> 4) * 4;
#pragma unroll
    for (int n = 0; n < 4; ++n) {
        const int gcol = tileN + wn * 64 + n * 16 + fcol;
        const float bc = bias[gcol];
#pragma unroll
        for (int m = 0; m < 8; ++m) {
            const int grow = tileM + wm * 128 + m * 16 + orow;
#pragma unroll
            for (int r = 0; r < 4; ++r)
                Y[(size_t)(grow + r) * D_HID + gcol] = f2bf(acc[m][n][r] + bc);
        }
    }
}

// ---------------------------------------------------------------------------
// Histogram threshold select on bf16 y: emit UNORDERED superset of the
// top-16 coarse elements per row (exact ranking by refine_decode).
// key16 = monotonic 16-bit transform of bf16 bits.
// v4: TARGET=16 and threshold = one bin BELOW the bin of the 16th-largest
// key. Bin = 16 bf16 ULPs (~0.25 value units at y~4), >=10x the coarse
// error bound, so the true top-16 are included with big margin while C
// drops from ~32-40 to ~18-22 -> refine traffic nearly halves.
// ---------------------------------------------------------------------------
__device__ __forceinline__ unsigned bf2key(unsigned u) {
    return (u & 0x8000u) ? (~u & 0xFFFFu) : (u | 0x8000u);
}

__global__ __launch_bounds__(256) void topk_select(
    const ushort_t* __restrict__ y,    // [chunkM, D_HID] bf16
    int* __restrict__ cand,            // [BATCH, CBUF]
    int* __restrict__ ccount,          // [BATCH]
    int rowBase)
{
    __shared__ unsigned hist[NBINS];   // 16 KB
    __shared__ unsigned psuf[257];
    __shared__ int sBstar;
    __shared__ unsigned scnt;

    const int tid = threadIdx.x;
    const int row = rowBase + blockIdx.x;
    const short8* yr8 = (const short8*)(y + (size_t)blockIdx.x * D_HID);

    for (int i = tid; i < NBINS; i += 256) hist[i] = 0;
    if (tid == 0) { sBstar = 0; scnt = 0; }
    __syncthreads();

    // Pass 1: histogram of key16 >> 4
    for (int j = 0; j < 8; ++j) {
        union { short8 v; ushort_t u[8]; } p;
        p.v = yr8[tid + j * 256];
#pragma unroll
        for (int c = 0; c < 8; ++c)
            atomicAdd(&hist[bf2key(p.u[c]) >> 4], 1u);
    }
    __syncthreads();

    {
        unsigned s = 0;
#pragma unroll
        for (int i = 0; i < 16; ++i) s += hist[tid * 16 + i];
        psuf[tid] = s;
    }
    __syncthreads();
    if (tid == 0) {
        unsigned run = 0;
        for (int t = 255; t >= 0; --t) { run += psuf[t]; psuf[t] = run; }
        psuf[256] = 0;
    }
    __syncthreads();
    {
        unsigned run = psuf[tid + 1];
        for (int b = tid * 16 + 15; b >= tid * 16; --b) {
            run += hist[b];
            if (run >= TARGET) { atomicMax(&sBstar, b); break; }
        }
    }
    __syncthreads();
    const int bT = (sBstar > 0) ? (sBstar - 1) : 0;   // one-bin margin
    const unsigned keyT = ((unsigned)bT) << 4;

    // Pass 2: compact candidate indices (unordered)
    for (int j = 0; j < 8; ++j) {
        const int i8 = tid + j * 256;
        union { short8 v; ushort_t u[8]; } p;
        p.v = yr8[i8];
#pragma unroll
        for (int c = 0; c < 8; ++c) {
            if (bf2key(p.u[c]) >= keyT) {
                unsigned pos = atomicAdd(&scnt, 1u);
                if (pos < CBUF) cand[(size_t)row * CBUF + pos] = i8 * 8 + c;
            }
        }
    }
    __syncthreads();
    if (tid == 0) ccount[row] = (int)min(scnt, (unsigned)CBUF);
}

// ---------------------------------------------------------------------------
// Fused fp64 refinement + decode.
//   phase 1: exact fp64 dots of the C candidates (2/iter, 16 staged float4)
//   phase 2: top-16 extraction.  Fast path (C<=64, now the common case):
//            lane c owns (sdot, h) in registers; 16 rounds of 6-step
//            __shfl_xor argmax (value desc, idx asc); winner lane
//            self-deactivates.  ZERO barriers in the loop (was 32).
//   phase 3: decode from L2-warm rows.
// ---------------------------------------------------------------------------
__global__ __launch_bounds__(256, 3) void refine_decode(
    const float* __restrict__ x,       // [BATCH, D_IN]
    const float* __restrict__ W,       // [D_HID, D_IN]
    const float* __restrict__ bias,    // [D_HID]
    const int* __restrict__ cand,      // [BATCH, CBUF]
    const int* __restrict__ ccount,    // [BATCH]
    float* __restrict__ out,           // [BATCH, D_IN]
    float* __restrict__ idxOut)        // [BATCH, TOPK] as float
{
    __shared__ double sdot[CBUF];      // 4 KB
    __shared__ int    sidx[CBUF];      // 2 KB
    __shared__ double rdv[4];
    __shared__ int    rdc[4];
    __shared__ float  ssv[TOPK];
    __shared__ int    ssi[TOPK];

    const int b = blockIdx.x;
    const int tid = threadIdx.x;
    const int C = ccount[b];

    for (int c = tid; c < C; c += 256) sidx[c] = cand[(size_t)b * CBUF + c];
    __syncthreads();

    const int wave = tid >> 6;
    const int lane = tid & 63;

    // x-row slices for this lane: same for every candidate -> registers.
    const float4* xg4 = (const float4*)(x + (size_t)b * D_IN);
    float4 xr[8];
#pragma unroll
    for (int i = 0; i < 8; ++i) xr[i] = xg4[lane + i * 64];

    // phase 1: exact fp64 dots, 2 candidates per iteration
    for (int c0 = wave; c0 < C; c0 += 8) {
        const int c1 = c0 + 4;
        const bool has1 = (c1 < C);
        const int h0 = sidx[c0];
        const int h1 = has1 ? sidx[c1] : h0;
        const float4* p0 = (const float4*)(W + (size_t)h0 * D_IN) + lane;
        const float4* p1 = (const float4*)(W + (size_t)h1 * D_IN) + lane;
        const float bh0 = bias[h0];
        const float bh1 = bias[h1];

        // stage all 16 loads before any use
        float4 u0 = p0[0],   v0 = p1[0];
        float4 u1 = p0[64],  v1 = p1[64];
        float4 u2 = p0[128], v2 = p1[128];
        float4 u3 = p0[192], v3 = p1[192];
        float4 u4 = p0[256], v4 = p1[256];
        float4 u5 = p0[320], v5 = p1[320];
        float4 u6 = p0[384], v6 = p1[384];
        float4 u7 = p0[448], v7 = p1[448];

        double a0 = 0.0, a1 = 0.0, a2 = 0.0, a3 = 0.0;
        double e0 = 0.0, e1 = 0.0, e2 = 0.0, e3 = 0.0;
#define FMA2(UU, VV, II) \
        a0 += (double)xr[II].x * (double)UU.x; e0 += (double)xr[II].x * (double)VV.x; \
        a1 += (double)xr[II].y * (double)UU.y; e1 += (double)xr[II].y * (double)VV.y; \
        a2 += (double)xr[II].z * (double)UU.z; e2 += (double)xr[II].z * (double)VV.z; \
        a3 += (double)xr[II].w * (double)UU.w; e3 += (double)xr[II].w * (double)VV.w;
        FMA2(u0, v0, 0) FMA2(u1, v1, 1) FMA2(u2, v2, 2) FMA2(u3, v3, 3)
        FMA2(u4, v4, 4) FMA2(u5, v5, 5) FMA2(u6, v6, 6) FMA2(u7, v7, 7)
#undef FMA2

        double r0 = (a0 + a1) + (a2 + a3);
        double r1 = (e0 + e1) + (e2 + e3);
#pragma unroll
        for (int off = 32; off > 0; off >>= 1) {
            r0 += __shfl_down(r0, off, 64);
            r1 += __shfl_down(r1, off, 64);
        }
        if (lane == 0) {
            sdot[c0] = r0 + (double)bh0;
            if (has1) sdot[c1] = r1 + (double)bh1;
        }
    }
    __syncthreads();

    // phase 2: top-16 (value desc, idx asc)
    if (C <= 64) {
        // fast path: wave 0 only, register-resident, no barriers in loop
        if (wave == 0) {
            double mv = -1.0e300;
            int mh = 0x7FFFFFFF;
            if (lane < C) { mv = sdot[lane]; mh = sidx[lane]; }
#pragma unroll
            for (int k = 0; k < TOPK; ++k) {
                double wv = mv; int wh = mh;
#pragma unroll
                for (int off = 32; off > 0; off >>= 1) {
                    double v2 = __shfl_xor(wv, off, 64);
                    int    h2 = __shfl_xor(wh, off, 64);
                    if (v2 > wv || (v2 == wv && h2 < wh)) { wv = v2; wh = h2; }
                }
                if (lane == 0) {
                    ssv[k] = (float)wv;
                    ssi[k] = wh;
                    idxOut[(size_t)b * TOPK + k] = (float)wh;
                }
                if (mh == wh && wh != 0x7FFFFFFF) { mv = -1.0e300; mh = 0x7FFFFFFF; }
            }
        }
        __syncthreads();
    } else {
        for (int k = 0; k < TOPK; ++k) {
            double bv = -1.0e300; int bc = -1;
            for (int c = tid; c < C; c += 256) {
                double v = sdot[c];
                if (v > bv || (v == bv && bc >= 0 && sidx[c] < sidx[bc])) {
                    bv = v; bc = c;
                }
            }
#pragma unroll
            for (int off = 32; off > 0; off >>= 1) {
                double v2 = __shfl_down(bv, off, 64);
                int    c2 = __shfl_down(bc, off, 64);
                bool better = (v2 > bv) ||
                    (v2 == bv && c2 >= 0 &&
                     (bc < 0 || sidx[c2] < sidx[bc]));
                if (better) { bv = v2; bc = c2; }
            }
            if (lane == 0) { rdv[wave] = bv; rdc[wave] = bc; }
            __syncthreads();
            if (tid == 0) {
                double fv = rdv[0]; int fc = rdc[0];
#pragma unroll
                for (int w = 1; w < 4; ++w) {
                    double v2 = rdv[w]; int c2 = rdc[w];
                    bool better = (v2 > fv) ||
                        (v2 == fv && c2 >= 0 &&
                         (fc < 0 || sidx[c2] < sidx[fc]));
                    if (better) { fv = v2; fc = c2; }
                }
                const int hsel = sidx[fc];
                ssv[k] = (float)fv;
                ssi[k] = hsel;
                idxOut[(size_t)b * TOPK + k] = (float)hsel;
                sdot[fc] = -1.0e300;
            }
            __syncthreads();
        }
    }

    // phase 3: fused decode — rows are L2/L3-warm from phase 1
    const float4* W4 = (const float4*)W;
    float4* out4 = (float4*)(out + (size_t)b * D_IN);
    for (int d4 = tid; d4 < D_IN / 4; d4 += 256) {
        float4 acc = {0.f, 0.f, 0.f, 0.f};
#pragma unroll
        for (int k = 0; k < TOPK; ++k) {
            float4 w = W4[(size_t)ssi[k] * (D_IN / 4) + d4];
            float s = ssv[k];
            acc.x += s * w.x; acc.y += s * w.y;
            acc.z += s * w.z; acc.w += s * w.w;
        }
        out4[d4] = acc;
    }
}

// ---------------------------------------------------------------------------
extern "C" void kernel_launch(void* const* d_in, const int* in_sizes, int n_in,
                              void* d_out, int out_size, void* d_ws, size_t ws_size,
                              hipStream_t stream)
{
    const float* x    = (const float*)d_in[0];  // [BATCH, D_IN]
    const float* Wenc = (const float*)d_in[1];  // [D_HID, D_IN]
    const float* bias = (const float*)d_in[2];  // [D_HID]
    // d_in[3] = w_emb_w — mathematically Wenc^T, unused.

    float* out    = (float*)d_out;                   // [BATCH, D_IN] fp32
    float* idxOut = out + (size_t)BATCH * D_IN;      // [BATCH, TOPK] as fp32

    char* ws = (char*)d_ws;
    size_t off = 0;
    int*      cand   = (int*)(ws + off);      off += (size_t)BATCH * CBUF * 4;   // 8 MB
    int*      ccount = (int*)(ws + off);      off += (size_t)BATCH * 4;
    off = (off + 255) & ~(size_t)255;
    ushort_t* xbf    = (ushort_t*)(ws + off); off += (size_t)BATCH * D_IN * 2;   // 16 MB
    ushort_t* wbf    = (ushort_t*)(ws + off); off += (size_t)D_HID * D_IN * 2;   // 64 MB
    const size_t head = (off + 255) & ~(size_t)255;
    ushort_t* ybf = (ushort_t*)(ws + head);

    int chunk = BATCH;
    while (chunk > 256 && head + (size_t)chunk * D_HID * 2 > ws_size) chunk >>= 1;

    const int nx8 = BATCH * D_IN / 8;       // 1,048,576
    const int nw8 = D_HID * D_IN / 8;       // 4,194,304
    convert_bf16<<<(nx8 + 255) / 256, 256, 0, stream>>>(x, xbf, nx8);
    convert_bf16<<<(nw8 + 255) / 256, 256, 0, stream>>>(Wenc, wbf, nw8);

    for (int r0 = 0; r0 < BATCH; r0 += chunk) {
        const int mtiles = chunk / 256;
        encode_mfma256<<<64 * mtiles, 512, 0, stream>>>(
            xbf + (size_t)r0 * D_IN, wbf, bias, ybf);
        topk_select<<<chunk, 256, 0, stream>>>(ybf, cand, ccount, r0);
    }
    refine_decode<<<BATCH, 256, 0, stream>>>(x, Wenc, bias, cand, ccount, out, idxOut);
}